// Round 1
// baseline (104.064 us; speedup 1.0000x reference)
//
#include <hip/hip_runtime.h>

// Softmax over last axis, rows=2048, cols=32000, fp32 in/out.
// Reference: e^x / sum(e^x), no max subtraction (inputs in [0,1)).
//
// Single-pass design: one 1024-thread block per row; each thread caches its
// 32 exp() values in registers (8 x float4) so the input is read from HBM
// exactly once and the output written exactly once (524 MB total traffic).

#define SM_THREADS 1024
#define SM_V 32000
#define SM_V4 8000            // float4 elements per row
#define SM_FULL 7             // 7 * 1024 = 7168 full-coverage iterations
#define SM_REM 832            // 8000 - 7168 remainder float4s

__global__ __launch_bounds__(SM_THREADS, 1)
void softmax_rowwise_kernel(const float* __restrict__ in,
                            float* __restrict__ out) {
    const int row = blockIdx.x;
    const size_t base = (size_t)row * SM_V;
    const float4* __restrict__ inrow  = reinterpret_cast<const float4*>(in + base);
    float4* __restrict__       outrow = reinterpret_cast<float4*>(out + base);
    const int tid = threadIdx.x;

    float4 e[8];
    float lsum = 0.0f;

    #pragma unroll
    for (int k = 0; k < SM_FULL; ++k) {
        float4 x = inrow[tid + k * SM_THREADS];
        float4 ev;
        ev.x = __expf(x.x);
        ev.y = __expf(x.y);
        ev.z = __expf(x.z);
        ev.w = __expf(x.w);
        e[k] = ev;
        lsum += (ev.x + ev.y) + (ev.z + ev.w);
    }
    if (tid < SM_REM) {
        float4 x = inrow[tid + SM_FULL * SM_THREADS];
        float4 ev;
        ev.x = __expf(x.x);
        ev.y = __expf(x.y);
        ev.z = __expf(x.z);
        ev.w = __expf(x.w);
        e[7] = ev;
        lsum += (ev.x + ev.y) + (ev.z + ev.w);
    }

    // Wave-level (64-lane) shuffle reduction.
    #pragma unroll
    for (int off = 32; off > 0; off >>= 1)
        lsum += __shfl_down(lsum, off, 64);

    // Block-level reduction across the 16 waves via LDS.
    __shared__ float wsum[SM_THREADS / 64];
    const int wave = tid >> 6;
    const int lane = tid & 63;
    if (lane == 0) wsum[wave] = lsum;
    __syncthreads();

    float total = 0.0f;
    #pragma unroll
    for (int i = 0; i < SM_THREADS / 64; ++i)
        total += wsum[i];   // broadcast LDS reads: conflict-free

    const float inv = 1.0f / total;

    #pragma unroll
    for (int k = 0; k < SM_FULL; ++k) {
        float4 ev = e[k];
        float4 o;
        o.x = ev.x * inv;
        o.y = ev.y * inv;
        o.z = ev.z * inv;
        o.w = ev.w * inv;
        outrow[tid + k * SM_THREADS] = o;
    }
    if (tid < SM_REM) {
        float4 ev = e[7];
        float4 o;
        o.x = ev.x * inv;
        o.y = ev.y * inv;
        o.z = ev.z * inv;
        o.w = ev.w * inv;
        outrow[tid + SM_FULL * SM_THREADS] = o;
    }
}

extern "C" void kernel_launch(void* const* d_in, const int* in_sizes, int n_in,
                              void* d_out, int out_size, void* d_ws, size_t ws_size,
                              hipStream_t stream) {
    (void)n_in; (void)d_ws; (void)ws_size; (void)out_size;
    const float* in = (const float*)d_in[0];
    float* out = (float*)d_out;
    const int rows = in_sizes[0] / SM_V;   // 2048
    softmax_rowwise_kernel<<<dim3(rows), dim3(SM_THREADS), 0, stream>>>(in, out);
}

// Round 2
// 91.770 us; speedup vs baseline: 1.1340x; 1.1340x over previous
//
#include <hip/hip_runtime.h>

// Softmax over last axis, rows=2048, cols=32000, fp32 in/out.
// Reference: e^x / sum(e^x), no max subtraction (inputs in [0,1)).
//
// Single-pass: one 1024-thread block per row; each thread caches its 32
// exp() values in registers (8 x float4) -> input read once, output written
// once (524 MB total). Nontemporal load/store: both streams are
// read-once/write-once, so bypassing L2/L3 avoids the two 262 MB streams
// thrashing the 256 MB L3.

#define SM_THREADS 1024
#define SM_V 32000
#define SM_FULL 7             // 7 * 1024 = 7168 full-coverage float4 iters
#define SM_REM 832            // 8000 - 7168 remainder float4s

typedef float f32x4 __attribute__((ext_vector_type(4)));

__global__ __launch_bounds__(SM_THREADS, 1)
void softmax_rowwise_kernel(const float* __restrict__ in,
                            float* __restrict__ out) {
    const int row = blockIdx.x;
    const size_t base = (size_t)row * SM_V;
    const f32x4* __restrict__ inrow  = reinterpret_cast<const f32x4*>(in + base);
    f32x4* __restrict__       outrow = reinterpret_cast<f32x4*>(out + base);
    const int tid = threadIdx.x;

    f32x4 e[8];
    float lsum = 0.0f;

    #pragma unroll
    for (int k = 0; k < SM_FULL; ++k) {
        f32x4 x = __builtin_nontemporal_load(&inrow[tid + k * SM_THREADS]);
        f32x4 ev;
        ev.x = __expf(x.x);
        ev.y = __expf(x.y);
        ev.z = __expf(x.z);
        ev.w = __expf(x.w);
        e[k] = ev;
        lsum += (ev.x + ev.y) + (ev.z + ev.w);
    }
    if (tid < SM_REM) {
        f32x4 x = __builtin_nontemporal_load(&inrow[tid + SM_FULL * SM_THREADS]);
        f32x4 ev;
        ev.x = __expf(x.x);
        ev.y = __expf(x.y);
        ev.z = __expf(x.z);
        ev.w = __expf(x.w);
        e[7] = ev;
        lsum += (ev.x + ev.y) + (ev.z + ev.w);
    }

    // Wave-level (64-lane) shuffle reduction.
    #pragma unroll
    for (int off = 32; off > 0; off >>= 1)
        lsum += __shfl_down(lsum, off, 64);

    // Block-level reduction across the 16 waves via LDS.
    __shared__ float wsum[SM_THREADS / 64];
    const int wave = tid >> 6;
    const int lane = tid & 63;
    if (lane == 0) wsum[wave] = lsum;
    __syncthreads();

    float total = 0.0f;
    #pragma unroll
    for (int i = 0; i < SM_THREADS / 64; ++i)
        total += wsum[i];   // broadcast LDS reads: conflict-free

    const float inv = 1.0f / total;

    #pragma unroll
    for (int k = 0; k < SM_FULL; ++k) {
        f32x4 ev = e[k];
        f32x4 o;
        o.x = ev.x * inv;
        o.y = ev.y * inv;
        o.z = ev.z * inv;
        o.w = ev.w * inv;
        __builtin_nontemporal_store(o, &outrow[tid + k * SM_THREADS]);
    }
    if (tid < SM_REM) {
        f32x4 ev = e[7];
        f32x4 o;
        o.x = ev.x * inv;
        o.y = ev.y * inv;
        o.z = ev.z * inv;
        o.w = ev.w * inv;
        __builtin_nontemporal_store(o, &outrow[tid + SM_FULL * SM_THREADS]);
    }
}

extern "C" void kernel_launch(void* const* d_in, const int* in_sizes, int n_in,
                              void* d_out, int out_size, void* d_ws, size_t ws_size,
                              hipStream_t stream) {
    (void)n_in; (void)d_ws; (void)ws_size; (void)out_size;
    const float* in = (const float*)d_in[0];
    float* out = (float*)d_out;
    const int rows = in_sizes[0] / SM_V;   // 2048
    softmax_rowwise_kernel<<<dim3(rows), dim3(SM_THREADS), 0, stream>>>(in, out);
}